// Round 12
// baseline (29.647 us; speedup 1.0000x reference)
//
#include <hip/hip_runtime.h>

// RandomResizedCrop N=128,C=3,H=W=256 fp32 — R9 (XCD-pinned, vlerp-first,
// barrier-free) + R12 micro-fixes: (1) all 3 ds_writes issued before any
// ds_read (one write->read stall instead of three); (2) 128-thread blocks
// (2 independent waves, finer dispatch granularity, same 32-wave occupancy).

constexpr int N_ = 128, C_ = 3, H_ = 256, W_ = 256, HW_ = H_ * W_;
constexpr int SEG_ = 264;   // skewed V-segment: x + (x>>5) maps 0..255 -> 0..262

typedef float f32x4 __attribute__((ext_vector_type(4)));

__device__ __forceinline__ void coord(float scale, float bias, float xf, int size,
                                      int& i0, float& w) {
    const float span = (float)size;
    const float two  = 2.0f * span;
    float xs  = (xf + 0.5f) * (2.0f / span) - 1.0f;
    float g   = scale * xs + bias;
    float pre = ((g + 1.0f) * span - 1.0f) * 0.5f;
    float t = fabsf(pre + 0.5f);
    t = t - two * floorf(t * (1.0f / two));   // exact fmod(t, 512), pow2 span
    t = (t > span) ? (two - t) : t;
    t -= 0.5f;
    t = fminf(fmaxf(t, 0.0f), span - 1.0f);
    float f = floorf(t);
    w  = t - f;
    i0 = (int)f;                              // i0 == size-1  =>  w == 0 exactly
}

__global__ __launch_bounds__(128)
void rrc_kernel(const float* __restrict__ in, const float* __restrict__ wh,
                float* __restrict__ out) {
    __shared__ float V[2 * C_ * SEG_];        // 6 wave-private segments, 6.3 KB
    const int b    = blockIdx.x;
    const int slot = b >> 3;                  // 0..2047
    const int n    = (b & 7) + 8 * (slot >> 7);   // image, pinned to XCD b&7
    const int tid  = threadIdx.x;
    const int wv   = tid >> 6;                // wave in block (0..1)
    const int xq   = tid & 63;                // x-quad: x = 4*xq..4*xq+3
    const int y    = (slot & 127) * 2 + wv;   // own output row

    const float w_s = wh[n * 4 + 0];
    const float h_s = wh[n * 4 + 1];
    const float w_b = wh[n * 4 + 2];
    const float h_b = wh[n * 4 + 3];

    // Own row's y-coordinate.
    int iy0; float wy;
    coord(h_s, h_b, (float)y, H_, iy0, wy);
    const int iy1 = min(iy0 + 1, H_ - 1);     // wy==0 when clamped

    // x-coords + skewed gather offsets (addr(x) = x + (x>>5), bijective).
    int offA[4], offB[4]; float wx[4];
#pragma unroll
    for (int j = 0; j < 4; ++j) {
        int i0;
        coord(w_s, w_b, (float)(xq * 4 + j), W_, i0, wx[j]);
        const int xb = min(i0 + 1, W_ - 1);   // wx==0 when clamped
        offA[j] = i0 + (i0 >> 5);
        offB[j] = xb + (xb >> 5);
    }

    // Preload all 3 channels' row pairs (6 coalesced f32x4 loads in flight).
    const float* __restrict__ inN = in + (size_t)n * C_ * HW_;
    f32x4 g0[C_], g1[C_];
#pragma unroll
    for (int c = 0; c < C_; ++c) {
        g0[c] = *reinterpret_cast<const f32x4*>(inN + c * HW_ + iy0 * W_ + xq * 4);
        g1[c] = *reinterpret_cast<const f32x4*>(inN + c * HW_ + iy1 * W_ + xq * 4);
    }

    float* __restrict__ outN = out + (size_t)n * C_ * HW_;
    const int woff = xq * 4 + (xq >> 3);      // skewed write offset
    float* const seg0 = &V[(wv * C_ + 0) * SEG_];
    float* const seg1 = &V[(wv * C_ + 1) * SEG_];
    float* const seg2 = &V[(wv * C_ + 2) * SEG_];

    // All vlerps, then ALL ds_writes, then all ds_reads (one w->r stall).
    const f32x4 v0 = g0[0] + wy * (g1[0] - g0[0]);
    const f32x4 v1 = g0[1] + wy * (g1[1] - g0[1]);
    const f32x4 v2 = g0[2] + wy * (g1[2] - g0[2]);
    *reinterpret_cast<f32x4*>(seg0 + woff) = v0;
    *reinterpret_cast<f32x4*>(seg1 + woff) = v1;
    *reinterpret_cast<f32x4*>(seg2 + woff) = v2;

    float a[C_][4], bb[C_][4];
#pragma unroll
    for (int c = 0; c < C_; ++c) {
        float* const seg = (c == 0) ? seg0 : (c == 1) ? seg1 : seg2;
#pragma unroll
        for (int j = 0; j < 4; ++j) {
            a[c][j]  = seg[offA[j]];
            bb[c][j] = seg[offB[j]];
        }
    }
#pragma unroll
    for (int c = 0; c < C_; ++c) {
        f32x4 o;
#pragma unroll
        for (int j = 0; j < 4; ++j)
            o[j] = a[c][j] + wx[j] * (bb[c][j] - a[c][j]);
        *reinterpret_cast<f32x4*>(outN + (c * H_ + y) * W_ + xq * 4) = o;
    }
}

extern "C" void kernel_launch(void* const* d_in, const int* in_sizes, int n_in,
                              void* d_out, int out_size, void* d_ws, size_t ws_size,
                              hipStream_t stream) {
    const float* in = (const float*)d_in[0];
    const float* wh = (const float*)d_in[1];
    float* out      = (float*)d_out;
    (void)in_sizes; (void)n_in; (void)out_size; (void)d_ws; (void)ws_size;

    dim3 grid(N_ * 128);  // 16384 blocks x 128 threads; 2 rows per block
    dim3 block(128);
    rrc_kernel<<<grid, block, 0, stream>>>(in, wh, out);
}